// Round 1
// 2024.920 us; speedup vs baseline: 1.8034x; 1.8034x over previous
//
#include <hip/hip_runtime.h>
#include <math.h>

#define B 512
#define H 256
#define L 256
#define T 64
#define V 128
#define LAYERS 2
#define SOS 0

// ---- workspace layout (in _Float16 elements) ----
// All weights stored f16, k8-blocked: [k8][out][8] -> each lane loads 16B
// (dwordx4), lanes contiguous -> 1KB/wave coalesced.
#define OFF_A 0                      // attn:  [64][256][8]  (K=512 over [e|h])
#define OFF_C 131072                 // comb:  [64][256][8]  (K=512 over [ap|e])
#define OFF_G 262144                 // gru:   [2 layers][6 mats][32][256][8]
#define GRU_LAYER_STRIDE (6 * 65536) // 393216
#define GRU_MAT_STRIDE 65536
#define OFF_O (OFF_G + LAYERS * GRU_LAYER_STRIDE) // out: [32][128][8]
#define WS_HALVES (OFF_O + 32768)    // 1,081,344 halves = 2.16 MB
// xT: [b][l8][h][8] f16 — the einsum operand, coalesced + L3-resident (67 MB)
#define OFF_XT WS_HALVES
#define XT_B_STRIDE (32 * 256 * 8)   // 65536 halves per batch row
#define XT_HALVES ((size_t)B * XT_B_STRIDE)
#define WS_NEED_BYTES ((size_t)(OFF_XT + XT_HALVES) * 2)

typedef _Float16 half8 __attribute__((ext_vector_type(8)));
typedef _Float16 half2t __attribute__((ext_vector_type(2)));
typedef unsigned int u32x4 __attribute__((ext_vector_type(4)));
typedef float f32x4 __attribute__((ext_vector_type(4)));

__device__ __forceinline__ float fdot2(half2t a, half2t b, float c) {
#if __has_builtin(__builtin_amdgcn_fdot2)
    return __builtin_amdgcn_fdot2(a, b, c, false);
#else
    return c + (float)a[0] * (float)b[0] + (float)a[1] * (float)b[1];
#endif
}

union H8 {
    half8 v;
    half2t p[4];
    u32x4 u;
};

// Non-temporal 16B load: keep the streaming xT out of L2 so the weight set
// (2.16 MB) stays L2-resident per XCD.
__device__ __forceinline__ half8 nt_load_h8(const _Float16* p) {
    H8 t;
    t.u = __builtin_nontemporal_load((const u32x4*)p);
    return t.v;
}

__device__ __forceinline__ float sigmoidf_(float v) {
    return 1.f / (1.f + __expf(-v));
}
__device__ __forceinline__ float fast_tanh(float v) {
    v = fminf(fmaxf(v, -15.f), 15.f);
    float e = __expf(-2.f * v);
    return (1.f - e) / (1.f + e);
}

// One-time repack of all weights to f16 k8-blocked layouts in ws.
__global__ void prep_pack(const float* __restrict__ attn_w,
                          const float* __restrict__ comb_w,
                          const float* __restrict__ gru_w_ih,
                          const float* __restrict__ gru_w_hh,
                          const float* __restrict__ out_w,
                          _Float16* __restrict__ ws) {
    int stride = gridDim.x * blockDim.x;
    for (int idx = blockIdx.x * blockDim.x + threadIdx.x; idx < WS_HALVES; idx += stride) {
        float val;
        if (idx < OFF_C) {
            int i = idx & 7, r = idx >> 3;
            int l = r & 255, k8 = r >> 8;
            val = attn_w[l * 512 + k8 * 8 + i];
        } else if (idx < OFF_G) {
            int e = idx - OFF_C;
            int i = e & 7, r = e >> 3;
            int hh = r & 255, k8 = r >> 8;
            val = comb_w[hh * 512 + k8 * 8 + i];
        } else if (idx < OFF_O) {
            int e = idx - OFF_G;
            int layer = e / GRU_LAYER_STRIDE;
            e -= layer * GRU_LAYER_STRIDE;
            int mat = e >> 16;
            e &= 65535;
            int i = e & 7, r = e >> 3;
            int j = r & 255, k8 = r >> 8;
            int k = k8 * 8 + i;
            const float* src = (mat < 3) ? gru_w_ih : gru_w_hh;
            int gate = (mat < 3) ? mat : mat - 3;
            val = src[layer * (768 * 256) + (gate * 256 + j) * 256 + k];
        } else {
            int e = idx - OFF_O;
            int i = e & 7, r = e >> 3;
            int v = r & 127, k8 = r >> 7;
            val = out_w[v * 256 + k8 * 8 + i];
        }
        ws[idx] = (_Float16)val;
    }
}

// x[b][h][l] fp32 -> xT[b][l8][h][8] f16 (k8-blocked over l, lane-coalesced
// writes: consecutive h -> consecutive 16B).
__global__ void prep_x(const float* __restrict__ x, _Float16* __restrict__ xt) {
    const int b = blockIdx.x;
    const int h = threadIdx.x;
    const float* xr = x + ((size_t)b * H + h) * L;
    _Float16* base = xt + (size_t)b * XT_B_STRIDE + h * 8;
#pragma unroll 4
    for (int k8 = 0; k8 < 32; ++k8) {
        float4 v0 = *(const float4*)(xr + k8 * 8);
        float4 v1 = *(const float4*)(xr + k8 * 8 + 4);
        half8 o;
        o[0] = (_Float16)v0.x; o[1] = (_Float16)v0.y;
        o[2] = (_Float16)v0.z; o[3] = (_Float16)v0.w;
        o[4] = (_Float16)v1.x; o[5] = (_Float16)v1.y;
        o[6] = (_Float16)v1.z; o[7] = (_Float16)v1.w;
        *(half8*)(base + k8 * 2048) = o;
    }
}

// 256 blocks x 512 threads, 1 block/CU on all 256 CUs. Block owns 2 batch
// rows. NEW vs previous round: the two 256-thread groups (G = tid>>8) now
// COOPERATE on both rows instead of each owning one row, so every weight
// cache line is fetched once per block instead of twice:
//   - attn/comb: K-split (G = K-half), f32 partials combined via LDS
//   - GRU:       mat-split (G0 = W_ih gates, G1 = W_hh gates) — no extra
//                reduction needed, the halves are summed in the gate eqs
//   - out:       K-split across the h<128 / h>=128 halves of each group
// All LDS activation reads stay wave-uniform broadcasts (conflict-free).
template <bool USE_XT>
__global__ __launch_bounds__(512, 2) void decoder_kernel(
    const float* __restrict__ x,        // [B][H][1][L] fp32
    const int* __restrict__ y,          // [B][T]
    const float* __restrict__ emb,      // [V][H]
    const float* __restrict__ attn_b,   // [L]
    const float* __restrict__ comb_b,   // [H]
    const float* __restrict__ gru_b_ih, // [2][3H]
    const float* __restrict__ gru_b_hh, // [2][3H]
    const float* __restrict__ out_b,    // [V]
    const _Float16* __restrict__ wsh,
    const _Float16* __restrict__ xt,    // [B][32][256][8] f16 (if USE_XT)
    float* __restrict__ out) {
    __shared__ __align__(16) _Float16 ehf[2][512];          // [row][e | h0] f16
    __shared__ __align__(16) _Float16 hfs[LAYERS][2][256];  // [layer][row][h] f16
    __shared__ __align__(16) float h32[LAYERS][2][256];     // fp32 blend state
    __shared__ __align__(16) _Float16 apf[2][256];          // applied f16
    __shared__ __align__(16) _Float16 gfv[2][256];          // comb output f16
    __shared__ __align__(16) _Float16 awf[2][256];          // attn weights f16
    __shared__ __align__(16) float aw32[2][256];            // attn weights fp32 (!USE_XT)
    __shared__ __align__(16) float pbuf[2][2][3][256];      // [G][row][slot][h] partials
    __shared__ __align__(16) float po[2][2][128];           // [khalf][row][v] logit partials
    __shared__ __align__(16) float lgbuf[2][128][33];       // [row][v][t&31] logp buffer (pad 33: conflict-free)

    const int tid = threadIdx.x;
    const int G = tid >> 8;      // cooperation group 0/1 (K-half or mat-half)
    const int h = tid & 255;     // output-unit index
    const int lane = tid & 63;
    const int w = tid >> 6;      // wave index 0..7
    const int b0 = blockIdx.x * 2;

    const _Float16* AW = wsh + OFF_A;
    const _Float16* CW = wsh + OFF_C;
    const _Float16* OW = wsh + OFF_O;

    // ---- preload biases into registers (constant thread role) ----
    const float ab = attn_b[h];
    const float cb = comb_b[h];
    const float ob = (h < V) ? out_b[h] : 0.f;
    float b_ir[LAYERS], b_iz[LAYERS], b_in[LAYERS], b_hr[LAYERS], b_hz[LAYERS], b_hn[LAYERS];
#pragma unroll
    for (int l = 0; l < LAYERS; ++l) {
        b_ir[l] = gru_b_ih[l * 768 + h];
        b_iz[l] = gru_b_ih[l * 768 + 256 + h];
        b_in[l] = gru_b_ih[l * 768 + 512 + h];
        b_hr[l] = gru_b_hh[l * 768 + h];
        b_hz[l] = gru_b_hh[l * 768 + 256 + h];
        b_hn[l] = gru_b_hh[l * 768 + 512 + h];
    }

    // ---- init state (G doubles as row index here) ----
#pragma unroll
    for (int l = 0; l < LAYERS; ++l) {
        h32[l][G][h] = 0.f;
        hfs[l][G][h] = (_Float16)0.f;
    }
    ehf[G][256 + h] = (_Float16)0.f;
    __syncthreads();

    for (int t = 0; t < T; ++t) {
        // ---- embedding gather: thread group G fills row G ----
        {
            int tok = (t == 0) ? SOS : y[(b0 + G) * T + (t - 1)];
            ehf[G][h] = (_Float16)emb[tok * H + h];
        }
        __syncthreads();

        // ---- attn scores, K-split: group G covers k in [256G, 256G+256) ----
        {
            float a00 = 0.f, a01 = 0.f, a10 = 0.f, a11 = 0.f;
            const _Float16* wp = AW + ((G * 32) << 11) + (h << 3);
            const _Float16* e0 = &ehf[0][G << 8];
            const _Float16* e1 = &ehf[1][G << 8];
#pragma unroll 4
            for (int k8 = 0; k8 < 32; ++k8) {
                H8 uw, u0, u1;
                uw.v = *(const half8*)(wp + (k8 << 11));
                u0.v = *(const half8*)(e0 + (k8 << 3));
                u1.v = *(const half8*)(e1 + (k8 << 3));
                a00 = fdot2(uw.p[0], u0.p[0], a00);
                a00 = fdot2(uw.p[1], u0.p[1], a00);
                a01 = fdot2(uw.p[2], u0.p[2], a01);
                a01 = fdot2(uw.p[3], u0.p[3], a01);
                a10 = fdot2(uw.p[0], u1.p[0], a10);
                a10 = fdot2(uw.p[1], u1.p[1], a10);
                a11 = fdot2(uw.p[2], u1.p[2], a11);
                a11 = fdot2(uw.p[3], u1.p[3], a11);
            }
            float bias = (G == 0) ? ab : 0.f;
            pbuf[G][0][0][h] = a00 + a01 + bias;
            pbuf[G][1][0][h] = a10 + a11 + bias;
        }
        __syncthreads();

        // ---- softmax over L: wave r handles row r; combines K-half partials ----
        if (w < 2) {
            const int r = w;
            float s0 = pbuf[0][r][0][lane] + pbuf[1][r][0][lane];
            float s1 = pbuf[0][r][0][lane + 64] + pbuf[1][r][0][lane + 64];
            float s2 = pbuf[0][r][0][lane + 128] + pbuf[1][r][0][lane + 128];
            float s3 = pbuf[0][r][0][lane + 192] + pbuf[1][r][0][lane + 192];
            float m = fmaxf(fmaxf(s0, s1), fmaxf(s2, s3));
            for (int off = 32; off; off >>= 1) m = fmaxf(m, __shfl_xor(m, off));
            float e0 = __expf(s0 - m), e1 = __expf(s1 - m);
            float e2 = __expf(s2 - m), e3 = __expf(s3 - m);
            float s = e0 + e1 + e2 + e3;
            for (int off = 32; off; off >>= 1) s += __shfl_xor(s, off);
            float inv = 1.f / s;
            e0 *= inv; e1 *= inv; e2 *= inv; e3 *= inv;
            if (USE_XT) {
                awf[r][lane] = (_Float16)e0;
                awf[r][lane + 64] = (_Float16)e1;
                awf[r][lane + 128] = (_Float16)e2;
                awf[r][lane + 192] = (_Float16)e3;
            } else {
                aw32[r][lane] = e0;
                aw32[r][lane + 64] = e1;
                aw32[r][lane + 128] = e2;
                aw32[r][lane + 192] = e3;
            }
            float* outA = out + (size_t)B * V * T + ((size_t)(b0 + r) * T + t) * L;
            __builtin_nontemporal_store(e0, outA + lane);
            __builtin_nontemporal_store(e1, outA + lane + 64);
            __builtin_nontemporal_store(e2, outA + lane + 128);
            __builtin_nontemporal_store(e3, outA + lane + 192);
        }
        __syncthreads();

        // ---- applied[h] = sum_l aw[l] * x[row][:,l,h]; thread = (row G, h) ----
        if (USE_XT) {
            const _Float16* xrow = xt + (size_t)(b0 + G) * XT_B_STRIDE + (h << 3);
            const _Float16* ap = &awf[G][0];
            float a0 = 0.f, a1 = 0.f;
#pragma unroll 4
            for (int k8 = 0; k8 < 32; ++k8) {
                H8 uw, ua;
                uw.v = nt_load_h8(xrow + (k8 << 11));   // non-temporal: don't evict weights
                ua.v = *(const half8*)(ap + (k8 << 3));
                a0 = fdot2(uw.p[0], ua.p[0], a0);
                a0 = fdot2(uw.p[1], ua.p[1], a0);
                a1 = fdot2(uw.p[2], ua.p[2], a1);
                a1 = fdot2(uw.p[3], ua.p[3], a1);
            }
            apf[G][h] = (_Float16)(a0 + a1);
        } else {
            const float* xrow = x + ((size_t)(b0 + G) * H + h) * L;
            float a0 = 0.f, a1 = 0.f;
#pragma unroll 4
            for (int l = 0; l < L; l += 8) {
                float4 x0 = *(const float4*)(xrow + l);
                float4 x1 = *(const float4*)(xrow + l + 4);
                float4 w0 = *(const float4*)&aw32[G][l];
                float4 w1 = *(const float4*)&aw32[G][l + 4];
                a0 += x0.x * w0.x + x0.y * w0.y + x0.z * w0.z + x0.w * w0.w;
                a1 += x1.x * w1.x + x1.y * w1.y + x1.z * w1.z + x1.w * w1.w;
            }
            apf[G][h] = (_Float16)(a0 + a1);
        }
        __syncthreads();

        // ---- comb, K-split: G0 covers applied half, G1 covers e half ----
        {
            float a00 = 0.f, a01 = 0.f, a10 = 0.f, a11 = 0.f;
            const _Float16* wp = CW + ((G * 32) << 11) + (h << 3);
            const _Float16* i0 = (G == 0) ? &apf[0][0] : &ehf[0][0];
            const _Float16* i1 = (G == 0) ? &apf[1][0] : &ehf[1][0];
#pragma unroll 4
            for (int k8 = 0; k8 < 32; ++k8) {
                H8 uw, u0, u1;
                uw.v = *(const half8*)(wp + (k8 << 11));
                u0.v = *(const half8*)(i0 + (k8 << 3));
                u1.v = *(const half8*)(i1 + (k8 << 3));
                a00 = fdot2(uw.p[0], u0.p[0], a00);
                a00 = fdot2(uw.p[1], u0.p[1], a00);
                a01 = fdot2(uw.p[2], u0.p[2], a01);
                a01 = fdot2(uw.p[3], u0.p[3], a01);
                a10 = fdot2(uw.p[0], u1.p[0], a10);
                a10 = fdot2(uw.p[1], u1.p[1], a10);
                a11 = fdot2(uw.p[2], u1.p[2], a11);
                a11 = fdot2(uw.p[3], u1.p[3], a11);
            }
            pbuf[G][0][1][h] = a00 + a01;
            pbuf[G][1][1][h] = a10 + a11;
        }
        __syncthreads();
        // comb combine + ReLU: thread (G,h) finalizes row G
        gfv[G][h] = (_Float16)fmaxf(pbuf[0][G][1][h] + pbuf[1][G][1][h] + cb, 0.f);
        __syncthreads();

        // ---- 2-layer GRU, mat-split: G0 -> W_ih gates, G1 -> W_hh gates ----
#pragma unroll
        for (int layer = 0; layer < LAYERS; ++layer) {
            const _Float16* GW = wsh + OFF_G + layer * GRU_LAYER_STRIDE + G * 3 * GRU_MAT_STRIDE;
            const _Float16* act0;
            const _Float16* act1;
            if (G == 0) {
                act0 = (layer == 0) ? &gfv[0][0] : &hfs[0][0][0];
                act1 = (layer == 0) ? &gfv[1][0] : &hfs[0][1][0];
            } else {
                act0 = &hfs[layer][0][0];
                act1 = &hfs[layer][1][0];
            }
            float aA0 = 0.f, aB0 = 0.f, aC0 = 0.f, aA1 = 0.f, aB1 = 0.f, aC1 = 0.f;
#pragma unroll 4
            for (int k8 = 0; k8 < 32; ++k8) {
                H8 w0, w1, w2, u0, u1;
                const int off = (k8 << 11) + (h << 3);
                w0.v = *(const half8*)(GW + off);
                w1.v = *(const half8*)(GW + GRU_MAT_STRIDE + off);
                w2.v = *(const half8*)(GW + 2 * GRU_MAT_STRIDE + off);
                u0.v = *(const half8*)(act0 + (k8 << 3));
                u1.v = *(const half8*)(act1 + (k8 << 3));
#pragma unroll
                for (int p = 0; p < 4; ++p) {
                    aA0 = fdot2(w0.p[p], u0.p[p], aA0);
                    aB0 = fdot2(w1.p[p], u0.p[p], aB0);
                    aC0 = fdot2(w2.p[p], u0.p[p], aC0);
                    aA1 = fdot2(w0.p[p], u1.p[p], aA1);
                    aB1 = fdot2(w1.p[p], u1.p[p], aB1);
                    aC1 = fdot2(w2.p[p], u1.p[p], aC1);
                }
            }
            pbuf[G][0][0][h] = aA0;
            pbuf[G][0][1][h] = aB0;
            pbuf[G][0][2][h] = aC0;
            pbuf[G][1][0][h] = aA1;
            pbuf[G][1][1][h] = aB1;
            pbuf[G][1][2][h] = aC1;
            __syncthreads();
            // combine: thread (G,h) finalizes row G, unit h
            {
                float gi_r = pbuf[0][G][0][h], gi_z = pbuf[0][G][1][h], gi_n = pbuf[0][G][2][h];
                float gh_r = pbuf[1][G][0][h], gh_z = pbuf[1][G][1][h], gh_n = pbuf[1][G][2][h];
                float rr = sigmoidf_(gi_r + b_ir[layer] + gh_r + b_hr[layer]);
                float zz = sigmoidf_(gi_z + b_iz[layer] + gh_z + b_hz[layer]);
                float nn = fast_tanh(gi_n + b_in[layer] + rr * (gh_n + b_hn[layer]));
                float hnew = (1.f - zz) * nn + zz * h32[layer][G][h];
                h32[layer][G][h] = hnew;
                hfs[layer][G][h] = (_Float16)hnew;
                if (layer == 0) ehf[G][256 + h] = (_Float16)hnew;
            }
            __syncthreads();
        }

        // ---- logits, 2-way K-split per row: thread (G, h) -> row G,
        //      v = h&127, K-half = h>>7 ----
        {
            const int v = h & 127;
            const int kh = h >> 7;
            const _Float16* hp = &hfs[1][G][0] + (kh << 7);
            const _Float16* wp = OW + ((kh * 16) << 10) + (v << 3);
            float a0 = 0.f, a1 = 0.f;
#pragma unroll 4
            for (int k8 = 0; k8 < 16; ++k8) {
                H8 uw, ua;
                uw.v = *(const half8*)(wp + (k8 << 10));
                ua.v = *(const half8*)(hp + (k8 << 3));
                a0 = fdot2(uw.p[0], ua.p[0], a0);
                a0 = fdot2(uw.p[1], ua.p[1], a0);
                a1 = fdot2(uw.p[2], ua.p[2], a1);
                a1 = fdot2(uw.p[3], ua.p[3], a1);
            }
            po[kh][G][v] = a0 + a1 + ((kh == 0) ? ob : 0.f);
        }
        __syncthreads();

        // ---- log_softmax over V: wave r handles row r; buffer into LDS ----
        if (w < 2) {
            const int r = w;
            float l0 = po[0][r][lane] + po[1][r][lane];
            float l1 = po[0][r][lane + 64] + po[1][r][lane + 64];
            float m = fmaxf(l0, l1);
            for (int off = 32; off; off >>= 1) m = fmaxf(m, __shfl_xor(m, off));
            float s = __expf(l0 - m) + __expf(l1 - m);
            for (int off = 32; off; off >>= 1) s += __shfl_xor(s, off);
            float lse = m + __logf(s);
            lgbuf[r][lane][t & 31] = l0 - lse;
            lgbuf[r][lane + 64][t & 31] = l1 - lse;
        }

        // ---- flush logp buffer every 32 steps: coalesced nt float4 stores ----
        if ((t & 31) == 31) {
            __syncthreads();
            const int tb = t & ~31;
#pragma unroll
            for (int c = 0; c < 4; ++c) {
                int fidx = c * 512 + tid;   // 0..2047 float4s
                int r = fidx >> 10;
                int rem = fidx & 1023;
                int v = rem >> 3;
                int tq = (rem & 7) << 2;
                f32x4 vec = {lgbuf[r][v][tq], lgbuf[r][v][tq + 1],
                             lgbuf[r][v][tq + 2], lgbuf[r][v][tq + 3]};
                float* dst = out + (size_t)(b0 + r) * V * T + (size_t)v * T + tb + tq;
                __builtin_nontemporal_store(vec, (f32x4*)dst);
            }
        }
        // no trailing barrier needed: next iteration's first __syncthreads()
        // (after the emb write, which touches only ehf[*][0..255]) orders the
        // lse/flush accesses before any conflicting reuse of pbuf/po/lgbuf.
    }
}

extern "C" void kernel_launch(void* const* d_in, const int* in_sizes, int n_in,
                              void* d_out, int out_size, void* d_ws, size_t ws_size,
                              hipStream_t stream) {
    const float* x = (const float*)d_in[0];
    const int* y = (const int*)d_in[1];
    const float* emb = (const float*)d_in[2];
    const float* attn_w = (const float*)d_in[3];
    const float* attn_b = (const float*)d_in[4];
    const float* comb_w = (const float*)d_in[5];
    const float* comb_b = (const float*)d_in[6];
    const float* gru_w_ih = (const float*)d_in[7];
    const float* gru_w_hh = (const float*)d_in[8];
    const float* gru_b_ih = (const float*)d_in[9];
    const float* gru_b_hh = (const float*)d_in[10];
    const float* out_w = (const float*)d_in[11];
    const float* out_b = (const float*)d_in[12];
    float* out = (float*)d_out;
    _Float16* ws = (_Float16*)d_ws;

    prep_pack<<<512, 256, 0, stream>>>(attn_w, comb_w, gru_w_ih, gru_w_hh, out_w, ws);
    if (ws_size >= WS_NEED_BYTES) {
        _Float16* xt = ws + OFF_XT;
        prep_x<<<B, 256, 0, stream>>>(x, xt);
        decoder_kernel<true><<<B / 2, 512, 0, stream>>>(
            x, y, emb, attn_b, comb_b, gru_b_ih, gru_b_hh, out_b, ws, xt, out);
    } else {
        decoder_kernel<false><<<B / 2, 512, 0, stream>>>(
            x, y, emb, attn_b, comb_b, gru_b_ih, gru_b_hh, out_b, ws, nullptr, out);
    }
}